// Round 8
// baseline (140.135 us; speedup 1.0000x reference)
//
#include <hip/hip_runtime.h>
#include <math.h>

#define NPROP 2048
#define NCLS 81
#define NFG 80
#define NBLK 80        // blocks in kernel 2; all co-resident (<< 256 CUs)
#define CAP 512        // per-class candidate cap (mean ~59, huge margin)
#define TOPC 100       // per-class survivors that can matter for global top-100
#define NB 1152        // score histogram buckets
#define BMIN 0x7A99    // bits(0.05f) >> 15

// ws layout:
//   bar  : int[16]       @ 0        (zeroed by kernel 1, block 0)
//   scnt : int[80]       @ 64       (fully written by kernel 2 pre-barrier)
//   surv : ull[80*100]   @ 384      DENSE, stride TOPC (end 64384)
//   cand : ull[2048*80]  @ 65536    slot map, written in full by kernel 1

#define LDS_FENCE() do { __builtin_amdgcn_wave_barrier(); \
    asm volatile("s_waitcnt lgkmcnt(0)" ::: "memory");     \
    __builtin_amdgcn_wave_barrier(); } while (0)

__device__ __forceinline__ void decode_clip(const float* __restrict__ props,
                                            const float* __restrict__ reg,
                                            int p, int cls, float out[4]) {
    float px1 = props[p * 4 + 0], py1 = props[p * 4 + 1];
    float px2 = props[p * 4 + 2], py2 = props[p * 4 + 3];
    float w = px2 - px1 + 1.0f;
    float h = py2 - py1 + 1.0f;
    float cx = px1 + 0.5f * w;
    float cy = py1 + 0.5f * h;
    const float* r = reg + (size_t)p * (NCLS * 4) + cls * 4;
    float dx = r[0] / 10.0f;
    float dy = r[1] / 10.0f;
    float dw = fminf(r[2] / 5.0f, 4.135166556742356f);
    float dh = fminf(r[3] / 5.0f, 4.135166556742356f);
    float pcx = dx * w + cx;
    float pcy = dy * h + cy;
    float pw = expf(dw) * w;
    float ph = expf(dh) * h;
    float x1 = pcx - 0.5f * pw;
    float y1 = pcy - 0.5f * ph;
    float x2 = pcx + 0.5f * pw - 1.0f;
    float y2 = pcy + 0.5f * ph - 1.0f;
    out[0] = fminf(fmaxf(x1, 0.0f), 1332.0f);
    out[1] = fminf(fmaxf(y1, 0.0f), 799.0f);
    out[2] = fminf(fmaxf(x2, 0.0f), 1332.0f);
    out[3] = fminf(fmaxf(y2, 0.0f), 799.0f);
}

// one wave per proposal row: softmax in registers, write the full slot map
// cand[p*80+c] = valid ? key : 0. Coalesced stores, no atomics, no memset.
__global__ __launch_bounds__(256) void softmax_scatter(const float* __restrict__ logits,
                                                       unsigned long long* __restrict__ cand,
                                                       int* __restrict__ bar) {
    if (blockIdx.x == 0 && threadIdx.x == 0) *bar = 0;
    int gw = (blockIdx.x * blockDim.x + threadIdx.x) >> 6;
    int lane = threadIdx.x & 63;
    if (gw >= NPROP) return;
    const float* row = logits + (size_t)gw * NCLS;
    float a = row[lane];                       // lane < 64 < 81
    bool hasb = (lane + 64) < NCLS;            // lanes 0..16
    float b = hasb ? row[lane + 64] : -INFINITY;
    float m = fmaxf(a, b);
    #pragma unroll
    for (int s = 32; s; s >>= 1) m = fmaxf(m, __shfl_xor(m, s));
    float ea = expf(a - m);
    float eb = hasb ? expf(b - m) : 0.0f;
    float sum = ea + eb;
    #pragma unroll
    for (int s = 32; s; s >>= 1) sum += __shfl_xor(sum, s);
    float pa = ea / sum;
    float pb = eb / sum;
    unsigned long long* crow = cand + (size_t)gw * NFG;
    unsigned int np = (unsigned int)(~gw);
    if (lane != 0) {                           // c = lane-1 in [0,63)
        crow[lane - 1] = (pa > 0.05f)
            ? (((unsigned long long)__float_as_uint(pa) << 32) | np) : 0ULL;
    }
    if (hasb) {                                // c = lane+63 in [63,80)
        crow[lane + 63] = (pb > 0.05f)
            ? (((unsigned long long)__float_as_uint(pb) << 32) | np) : 0ULL;
    }
}

// 80 blocks x 256: wave 0 of each block does per-class NMS; grid barrier;
// block 0 does the dense radix-select top-100.
__global__ __launch_bounds__(256) void nms_topk(const unsigned long long* __restrict__ cand,
                                                const float* __restrict__ props,
                                                const float* __restrict__ reg,
                                                int* __restrict__ bar,
                                                int* __restrict__ scnt,
                                                unsigned long long* __restrict__ surv,
                                                float* __restrict__ out) {
    const int c = blockIdx.x;
    const int tid = threadIdx.x;
    const int lane = tid & 63;
    const int bw = tid >> 6;
    __shared__ unsigned long long keys[CAP];   // 4096 B
    __shared__ float4 bxs[CAP];                // 8192 B
    __shared__ unsigned int hist[NB];          // 4608 B
    __shared__ unsigned long long comp[1024];  // 8192 B
    __shared__ int s_n[NFG];
    __shared__ int sB;
    __shared__ int compN;

    // ---------------- per-class NMS on wave 0 ----------------
    if (bw == 0) {
        // ballot-compact this class's valid slots (p-ascending order:
        // equal scores later sort by smaller p first via ~p in the key)
        int base = 0;
        for (int p0 = 0; p0 < NPROP; p0 += 64) {
            unsigned long long key = cand[(size_t)(p0 + lane) * NFG + c];
            bool keep = key != 0ULL;
            unsigned long long mask = __ballot(keep);
            if (keep) {
                int pos = base + __popcll(mask & ((1ULL << lane) - 1ULL));
                if (pos < CAP) keys[pos] = key;
            }
            base += __popcll(mask);
        }
        int M = base > CAP ? CAP : base;
        int nsurv = 0;
        if (M > 0) {
            int S = 64;
            while (S < M) S <<= 1;
            for (int i = lane; i < S; i += 64)
                if (i >= M) keys[i] = 0ULL;
            LDS_FENCE();

            // wave-synchronous bitonic sort descending (pads sink to back)
            for (int k = 2; k <= S; k <<= 1) {
                for (int j = k >> 1; j > 0; j >>= 1) {
                    for (int i = lane; i < S; i += 64) {
                        int l = i ^ j;
                        if (l > i) {
                            unsigned long long A = keys[i], B = keys[l];
                            bool dir = ((i & k) == 0);
                            if ((A < B) == dir) { keys[i] = B; keys[l] = A; }
                        }
                    }
                    LDS_FENCE();
                }
            }

            // decode boxes: own slots to registers, all to LDS for broadcast
            float4 myb[8];
            #pragma unroll
            for (int ns = 0; ns < 8; ++ns) {
                int idx = lane + ns * 64;
                if (idx < M) {
                    unsigned long long key = keys[idx];
                    int p = (int)(~(unsigned int)key);
                    float b4[4];
                    decode_clip(props, reg, p, c + 1, b4);
                    float4 f = make_float4(b4[0], b4[1], b4[2], b4[3]);
                    myb[ns] = f;
                    bxs[idx] = f;
                }
            }
            LDS_FENCE();

            // greedy NMS: sequential i, suppression bits in registers
            unsigned int my_sup = 0u;
            for (int i = 0; i < M; ++i) {
                int owner = i & 63, slot = i >> 6;
                unsigned int os = __shfl(my_sup, owner);
                if ((os >> slot) & 1u) continue;   // wave-uniform
                float4 bi = bxs[i];                // broadcast LDS read
                float ai = (bi.z - bi.x + 1.0f) * (bi.w - bi.y + 1.0f);
                #pragma unroll
                for (int ns = 0; ns < 8; ++ns) {
                    int j = lane + ns * 64;
                    if (j < M && j > i) {
                        float4 bj = myb[ns];
                        float aj = (bj.z - bj.x + 1.0f) * (bj.w - bj.y + 1.0f);
                        float ltx = fmaxf(bi.x, bj.x), lty = fmaxf(bi.y, bj.y);
                        float rbx = fminf(bi.z, bj.z), rby = fminf(bi.w, bj.w);
                        float iw = fmaxf(rbx - ltx + 1.0f, 0.0f);
                        float ih = fmaxf(rby - lty + 1.0f, 0.0f);
                        float inter = iw * ih;
                        float iou = inter / (ai + aj - inter);
                        if (iou > 0.5f) my_sup |= (1u << ns);
                    }
                }
            }

            // ballot-compact survivors (descending order), re-key with ~flat;
            // only the first TOPC per class matter -> dense stride TOPC.
            #pragma unroll
            for (int ns = 0; ns < 8; ++ns) {
                if (ns * 64 >= M) break;           // uniform
                int j = lane + ns * 64;
                bool keep = (j < M) && !((my_sup >> ns) & 1u);
                unsigned long long mask = __ballot(keep);
                if (keep) {
                    int pos = nsurv + __popcll(mask & ((1ULL << lane) - 1ULL));
                    if (pos < TOPC) {
                        unsigned long long key = keys[j];
                        int p = (int)(~(unsigned int)key);
                        unsigned int flat = (unsigned int)(c * NPROP + p);
                        surv[c * TOPC + pos] =
                            (key & 0xFFFFFFFF00000000ULL) | (unsigned int)(~flat);
                    }
                }
                nsurv += __popcll(mask);
            }
        }
        if (lane == 0) scnt[c] = nsurv;
    }

    // ---------------- grid barrier: survivors visible ----------------
    __syncthreads();
    if (tid == 0) {
        __threadfence();
        atomicAdd(bar, 1);
    }
    if (blockIdx.x != 0) return;
    if (tid == 0) {
        int guard = 0;
        while (__hip_atomic_load(bar, __ATOMIC_ACQUIRE,
                                 __HIP_MEMORY_SCOPE_AGENT) < NBLK) {
            if (++guard > (1 << 24)) break;       // never hang the replay
        }
    }
    __syncthreads();
    __threadfence();

    // ---------------- block 0: radix-select top-100 ----------------
    for (int i = tid; i < NB; i += 256) hist[i] = 0u;
    if (tid < NFG) {
        int k = scnt[tid];
        s_n[tid] = (k > TOPC) ? TOPC : k;
    }
    if (tid == 0) compN = 0;
    __syncthreads();

    for (int idx = tid; idx < NFG * TOPC; idx += 256) {
        int cc = idx / TOPC, i = idx - cc * TOPC;
        if (i < s_n[cc]) {
            unsigned long long key = surv[idx];
            int b = (int)(((unsigned int)(key >> 32)) >> 15) - BMIN;
            b = b < 0 ? 0 : (b >= NB ? NB - 1 : b);
            atomicAdd(&hist[b], 1u);
        }
    }
    __syncthreads();

    // wave 0: suffix-sum from top to find threshold bucket (cum >= 100)
    if (tid < 64) {
        int running = 0, Bstar = 0;
        bool found = false;
        for (int chunk = NB - 64; chunk >= 0; chunk -= 64) {
            int b = chunk + 63 - tid;              // lane 0 = highest bucket
            int s = (int)hist[b];
            #pragma unroll
            for (int d = 1; d < 64; d <<= 1) {
                int o = __shfl_up(s, d);
                if (tid >= d) s += o;
            }
            int cum = running + s;
            unsigned long long m = __ballot(cum >= TOPC);
            if (m != 0ULL) {
                int l = (int)__ffsll((unsigned long long)m) - 1;
                Bstar = chunk + 63 - l;
                found = true;
                break;
            }
            running += __shfl(s, 63);
        }
        if (!found) Bstar = 0;
        if (tid == 0) sB = Bstar;
    }
    __syncthreads();
    int Bstar = sB;

    for (int idx = tid; idx < NFG * TOPC; idx += 256) {
        int cc = idx / TOPC, i = idx - cc * TOPC;
        if (i < s_n[cc]) {
            unsigned long long key = surv[idx];
            int b = (int)(((unsigned int)(key >> 32)) >> 15) - BMIN;
            b = b < 0 ? 0 : (b >= NB ? NB - 1 : b);
            if (b >= Bstar) {
                int pos = atomicAdd(&compN, 1);
                if (pos < 1024) comp[pos] = key;
            }
        }
    }
    __syncthreads();
    int K = compN;
    if (K > 1024) K = 1024;
    int P = 128;
    while (P < K) P <<= 1;
    for (int i = K + tid; i < P; i += 256) comp[i] = 0ULL;
    __syncthreads();

    // wave 0: wave-synchronous bitonic sort descending over comp[0..P)
    if (tid < 64) {
        for (int k = 2; k <= P; k <<= 1) {
            for (int j = k >> 1; j > 0; j >>= 1) {
                for (int i = tid; i < P; i += 64) {
                    int l = i ^ j;
                    if (l > i) {
                        unsigned long long A = comp[i], B = comp[l];
                        bool dir = ((i & k) == 0);
                        if ((A < B) == dir) { comp[i] = B; comp[l] = A; }
                    }
                }
                LDS_FENCE();
            }
        }
    }
    __syncthreads();

    if (tid < TOPC) {
        unsigned long long key = comp[tid];
        float score;
        int flat;
        if (key == 0ULL) {             // < 100 total survivors: not expected
            score = -1.0f;
            flat = tid;
        } else {
            score = __uint_as_float((unsigned int)(key >> 32));
            flat = (int)(~(unsigned int)key);
        }
        int cc = flat >> 11;           // NPROP = 2^11
        int p = flat & (NPROP - 1);
        float b4[4];
        decode_clip(props, reg, p, cc + 1, b4);
        out[tid * 4 + 0] = b4[0];
        out[tid * 4 + 1] = b4[1];
        out[tid * 4 + 2] = b4[2];
        out[tid * 4 + 3] = b4[3];
        out[400 + tid] = score;
        out[500 + tid] = (float)(cc + 1);
    }
}

extern "C" void kernel_launch(void* const* d_in, const int* in_sizes, int n_in,
                              void* d_out, int out_size, void* d_ws, size_t ws_size,
                              hipStream_t stream) {
    const float* logits = (const float*)d_in[0];
    const float* reg    = (const float*)d_in[1];
    const float* props  = (const float*)d_in[2];
    float* out = (float*)d_out;

    int* bar  = (int*)d_ws;
    int* scnt = (int*)((char*)d_ws + 64);
    unsigned long long* surv = (unsigned long long*)((char*)d_ws + 384);
    unsigned long long* cand = (unsigned long long*)((char*)d_ws + 65536);

    hipLaunchKernelGGL(softmax_scatter, dim3((NPROP * 64) / 256), dim3(256), 0, stream,
                       logits, cand, bar);
    hipLaunchKernelGGL(nms_topk, dim3(NBLK), dim3(256), 0, stream,
                       cand, props, reg, bar, scnt, surv, out);
}

// Round 9
// 139.085 us; speedup vs baseline: 1.0076x; 1.0076x over previous
//
#include <hip/hip_runtime.h>
#include <math.h>

#define NPROP 2048
#define NCLS 81
#define NFG 80
#define NBLK 80        // blocks in kernel 2; all co-resident (<< 256 CUs)
#define CAP 512        // per-class candidate cap (mean ~59, huge margin)
#define TOPC 100       // per-class survivors that can matter for global top-100
#define NB 1152        // score histogram buckets
#define BMIN 0x7A99    // bits(0.05f) >> 15

// ws layout:
//   bar  : int[16]       @ 0        (zeroed by kernel 1, block 0)
//   scnt : int[80]       @ 64       (fully written by kernel 2 pre-barrier)
//   surv : ull[80*100]   @ 384      DENSE, stride TOPC (end 64384)
//   cand : ull[80*2048]  @ 65536    CLASS-MAJOR slot map, fully written by k1

#define LDS_FENCE() do { __builtin_amdgcn_wave_barrier(); \
    asm volatile("s_waitcnt lgkmcnt(0)" ::: "memory");     \
    __builtin_amdgcn_wave_barrier(); } while (0)

__device__ __forceinline__ void decode_clip(const float* __restrict__ props,
                                            const float* __restrict__ reg,
                                            int p, int cls, float out[4]) {
    float px1 = props[p * 4 + 0], py1 = props[p * 4 + 1];
    float px2 = props[p * 4 + 2], py2 = props[p * 4 + 3];
    float w = px2 - px1 + 1.0f;
    float h = py2 - py1 + 1.0f;
    float cx = px1 + 0.5f * w;
    float cy = py1 + 0.5f * h;
    const float* r = reg + (size_t)p * (NCLS * 4) + cls * 4;
    float dx = r[0] / 10.0f;
    float dy = r[1] / 10.0f;
    float dw = fminf(r[2] / 5.0f, 4.135166556742356f);
    float dh = fminf(r[3] / 5.0f, 4.135166556742356f);
    float pcx = dx * w + cx;
    float pcy = dy * h + cy;
    float pw = expf(dw) * w;
    float ph = expf(dh) * h;
    float x1 = pcx - 0.5f * pw;
    float y1 = pcy - 0.5f * ph;
    float x2 = pcx + 0.5f * pw - 1.0f;
    float y2 = pcy + 0.5f * ph - 1.0f;
    out[0] = fminf(fmaxf(x1, 0.0f), 1332.0f);
    out[1] = fminf(fmaxf(y1, 0.0f), 799.0f);
    out[2] = fminf(fmaxf(x2, 0.0f), 1332.0f);
    out[3] = fminf(fmaxf(y2, 0.0f), 799.0f);
}

// one wave per proposal row: softmax in registers, write the class-major
// slot map cand[c*2048+p] = valid ? key : 0. No atomics, no memset.
// Stores are scattered (stride 16KB) but fire-and-forget; L2 write-combines.
__global__ __launch_bounds__(256) void softmax_scatter(const float* __restrict__ logits,
                                                       unsigned long long* __restrict__ cand,
                                                       int* __restrict__ bar) {
    if (blockIdx.x == 0 && threadIdx.x == 0) *bar = 0;
    int gw = (blockIdx.x * blockDim.x + threadIdx.x) >> 6;
    int lane = threadIdx.x & 63;
    if (gw >= NPROP) return;
    const float* row = logits + (size_t)gw * NCLS;
    float a = row[lane];                       // lane < 64 < 81
    bool hasb = (lane + 64) < NCLS;            // lanes 0..16
    float b = hasb ? row[lane + 64] : -INFINITY;
    float m = fmaxf(a, b);
    #pragma unroll
    for (int s = 32; s; s >>= 1) m = fmaxf(m, __shfl_xor(m, s));
    float ea = expf(a - m);
    float eb = hasb ? expf(b - m) : 0.0f;
    float sum = ea + eb;
    #pragma unroll
    for (int s = 32; s; s >>= 1) sum += __shfl_xor(sum, s);
    float pa = ea / sum;
    float pb = eb / sum;
    unsigned int np = (unsigned int)(~gw);
    if (lane != 0) {                           // c = lane-1 in [0,63)
        cand[(size_t)(lane - 1) * NPROP + gw] = (pa > 0.05f)
            ? (((unsigned long long)__float_as_uint(pa) << 32) | np) : 0ULL;
    }
    if (hasb) {                                // c = lane+63 in [63,80)
        cand[(size_t)(lane + 63) * NPROP + gw] = (pb > 0.05f)
            ? (((unsigned long long)__float_as_uint(pb) << 32) | np) : 0ULL;
    }
}

// 80 blocks x 256: wave 0 of each block does per-class NMS (coalesced 16KB
// column gather); grid barrier; block 0 does the dense radix-select top-100.
__global__ __launch_bounds__(256) void nms_topk(const unsigned long long* __restrict__ cand,
                                                const float* __restrict__ props,
                                                const float* __restrict__ reg,
                                                int* __restrict__ bar,
                                                int* __restrict__ scnt,
                                                unsigned long long* __restrict__ surv,
                                                float* __restrict__ out) {
    const int c = blockIdx.x;
    const int tid = threadIdx.x;
    const int lane = tid & 63;
    const int bw = tid >> 6;
    __shared__ unsigned long long keys[CAP];   // 4096 B
    __shared__ float4 bxs[CAP];                // 8192 B
    __shared__ unsigned int hist[NB];          // 4608 B
    __shared__ unsigned long long comp[1024];  // 8192 B
    __shared__ int s_n[NFG];
    __shared__ int sB;
    __shared__ int compN;

    // ---------------- per-class NMS on wave 0 ----------------
    if (bw == 0) {
        // ballot-compact this class's valid slots (p-ascending order:
        // equal scores later sort by smaller p first via ~p in the key)
        const unsigned long long* col = cand + (size_t)c * NPROP;
        int base = 0;
        for (int p0 = 0; p0 < NPROP; p0 += 64) {
            unsigned long long key = col[p0 + lane];   // coalesced 512B
            bool keep = key != 0ULL;
            unsigned long long mask = __ballot(keep);
            if (keep) {
                int pos = base + __popcll(mask & ((1ULL << lane) - 1ULL));
                if (pos < CAP) keys[pos] = key;
            }
            base += __popcll(mask);
        }
        int M = base > CAP ? CAP : base;
        int nsurv = 0;
        if (M > 0) {
            int S = 64;
            while (S < M) S <<= 1;
            for (int i = lane; i < S; i += 64)
                if (i >= M) keys[i] = 0ULL;
            LDS_FENCE();

            // wave-synchronous bitonic sort descending (pads sink to back)
            for (int k = 2; k <= S; k <<= 1) {
                for (int j = k >> 1; j > 0; j >>= 1) {
                    for (int i = lane; i < S; i += 64) {
                        int l = i ^ j;
                        if (l > i) {
                            unsigned long long A = keys[i], B = keys[l];
                            bool dir = ((i & k) == 0);
                            if ((A < B) == dir) { keys[i] = B; keys[l] = A; }
                        }
                    }
                    LDS_FENCE();
                }
            }

            // decode boxes: own slots to registers, all to LDS for broadcast
            float4 myb[8];
            #pragma unroll
            for (int ns = 0; ns < 8; ++ns) {
                int idx = lane + ns * 64;
                if (idx < M) {
                    unsigned long long key = keys[idx];
                    int p = (int)(~(unsigned int)key);
                    float b4[4];
                    decode_clip(props, reg, p, c + 1, b4);
                    float4 f = make_float4(b4[0], b4[1], b4[2], b4[3]);
                    myb[ns] = f;
                    bxs[idx] = f;
                }
            }
            LDS_FENCE();

            // greedy NMS: sequential i, suppression bits in registers
            unsigned int my_sup = 0u;
            for (int i = 0; i < M; ++i) {
                int owner = i & 63, slot = i >> 6;
                unsigned int os = __shfl(my_sup, owner);
                if ((os >> slot) & 1u) continue;   // wave-uniform
                float4 bi = bxs[i];                // broadcast LDS read
                float ai = (bi.z - bi.x + 1.0f) * (bi.w - bi.y + 1.0f);
                #pragma unroll
                for (int ns = 0; ns < 8; ++ns) {
                    int j = lane + ns * 64;
                    if (j < M && j > i) {
                        float4 bj = myb[ns];
                        float aj = (bj.z - bj.x + 1.0f) * (bj.w - bj.y + 1.0f);
                        float ltx = fmaxf(bi.x, bj.x), lty = fmaxf(bi.y, bj.y);
                        float rbx = fminf(bi.z, bj.z), rby = fminf(bi.w, bj.w);
                        float iw = fmaxf(rbx - ltx + 1.0f, 0.0f);
                        float ih = fmaxf(rby - lty + 1.0f, 0.0f);
                        float inter = iw * ih;
                        float iou = inter / (ai + aj - inter);
                        if (iou > 0.5f) my_sup |= (1u << ns);
                    }
                }
            }

            // ballot-compact survivors (descending order), re-key with ~flat;
            // only the first TOPC per class matter -> dense stride TOPC.
            #pragma unroll
            for (int ns = 0; ns < 8; ++ns) {
                if (ns * 64 >= M) break;           // uniform
                int j = lane + ns * 64;
                bool keep = (j < M) && !((my_sup >> ns) & 1u);
                unsigned long long mask = __ballot(keep);
                if (keep) {
                    int pos = nsurv + __popcll(mask & ((1ULL << lane) - 1ULL));
                    if (pos < TOPC) {
                        unsigned long long key = keys[j];
                        int p = (int)(~(unsigned int)key);
                        unsigned int flat = (unsigned int)(c * NPROP + p);
                        surv[c * TOPC + pos] =
                            (key & 0xFFFFFFFF00000000ULL) | (unsigned int)(~flat);
                    }
                }
                nsurv += __popcll(mask);
            }
        }
        if (lane == 0) scnt[c] = nsurv;
    }

    // ---------------- grid barrier: survivors visible ----------------
    __syncthreads();
    if (tid == 0) {
        __threadfence();
        atomicAdd(bar, 1);
    }
    if (blockIdx.x != 0) return;
    if (tid == 0) {
        int guard = 0;
        while (__hip_atomic_load(bar, __ATOMIC_ACQUIRE,
                                 __HIP_MEMORY_SCOPE_AGENT) < NBLK) {
            if (++guard > (1 << 24)) break;       // never hang the replay
        }
    }
    __syncthreads();
    __threadfence();

    // ---------------- block 0: radix-select top-100 ----------------
    for (int i = tid; i < NB; i += 256) hist[i] = 0u;
    if (tid < NFG) {
        int k = scnt[tid];
        s_n[tid] = (k > TOPC) ? TOPC : k;
    }
    if (tid == 0) compN = 0;
    __syncthreads();

    for (int idx = tid; idx < NFG * TOPC; idx += 256) {
        int cc = idx / TOPC, i = idx - cc * TOPC;
        if (i < s_n[cc]) {
            unsigned long long key = surv[idx];
            int b = (int)(((unsigned int)(key >> 32)) >> 15) - BMIN;
            b = b < 0 ? 0 : (b >= NB ? NB - 1 : b);
            atomicAdd(&hist[b], 1u);
        }
    }
    __syncthreads();

    // wave 0: suffix-sum from top to find threshold bucket (cum >= 100)
    if (tid < 64) {
        int running = 0, Bstar = 0;
        bool found = false;
        for (int chunk = NB - 64; chunk >= 0; chunk -= 64) {
            int b = chunk + 63 - tid;              // lane 0 = highest bucket
            int s = (int)hist[b];
            #pragma unroll
            for (int d = 1; d < 64; d <<= 1) {
                int o = __shfl_up(s, d);
                if (tid >= d) s += o;
            }
            int cum = running + s;
            unsigned long long m = __ballot(cum >= TOPC);
            if (m != 0ULL) {
                int l = (int)__ffsll((unsigned long long)m) - 1;
                Bstar = chunk + 63 - l;
                found = true;
                break;
            }
            running += __shfl(s, 63);
        }
        if (!found) Bstar = 0;
        if (tid == 0) sB = Bstar;
    }
    __syncthreads();
    int Bstar = sB;

    for (int idx = tid; idx < NFG * TOPC; idx += 256) {
        int cc = idx / TOPC, i = idx - cc * TOPC;
        if (i < s_n[cc]) {
            unsigned long long key = surv[idx];
            int b = (int)(((unsigned int)(key >> 32)) >> 15) - BMIN;
            b = b < 0 ? 0 : (b >= NB ? NB - 1 : b);
            if (b >= Bstar) {
                int pos = atomicAdd(&compN, 1);
                if (pos < 1024) comp[pos] = key;
            }
        }
    }
    __syncthreads();
    int K = compN;
    if (K > 1024) K = 1024;
    int P = 128;
    while (P < K) P <<= 1;
    for (int i = K + tid; i < P; i += 256) comp[i] = 0ULL;
    __syncthreads();

    // wave 0: wave-synchronous bitonic sort descending over comp[0..P)
    if (tid < 64) {
        for (int k = 2; k <= P; k <<= 1) {
            for (int j = k >> 1; j > 0; j >>= 1) {
                for (int i = tid; i < P; i += 64) {
                    int l = i ^ j;
                    if (l > i) {
                        unsigned long long A = comp[i], B = comp[l];
                        bool dir = ((i & k) == 0);
                        if ((A < B) == dir) { comp[i] = B; comp[l] = A; }
                    }
                }
                LDS_FENCE();
            }
        }
    }
    __syncthreads();

    if (tid < TOPC) {
        unsigned long long key = comp[tid];
        float score;
        int flat;
        if (key == 0ULL) {             // < 100 total survivors: not expected
            score = -1.0f;
            flat = tid;
        } else {
            score = __uint_as_float((unsigned int)(key >> 32));
            flat = (int)(~(unsigned int)key);
        }
        int cc = flat >> 11;           // NPROP = 2^11
        int p = flat & (NPROP - 1);
        float b4[4];
        decode_clip(props, reg, p, cc + 1, b4);
        out[tid * 4 + 0] = b4[0];
        out[tid * 4 + 1] = b4[1];
        out[tid * 4 + 2] = b4[2];
        out[tid * 4 + 3] = b4[3];
        out[400 + tid] = score;
        out[500 + tid] = (float)(cc + 1);
    }
}

extern "C" void kernel_launch(void* const* d_in, const int* in_sizes, int n_in,
                              void* d_out, int out_size, void* d_ws, size_t ws_size,
                              hipStream_t stream) {
    const float* logits = (const float*)d_in[0];
    const float* reg    = (const float*)d_in[1];
    const float* props  = (const float*)d_in[2];
    float* out = (float*)d_out;

    int* bar  = (int*)d_ws;
    int* scnt = (int*)((char*)d_ws + 64);
    unsigned long long* surv = (unsigned long long*)((char*)d_ws + 384);
    unsigned long long* cand = (unsigned long long*)((char*)d_ws + 65536);

    hipLaunchKernelGGL(softmax_scatter, dim3((NPROP * 64) / 256), dim3(256), 0, stream,
                       logits, cand, bar);
    hipLaunchKernelGGL(nms_topk, dim3(NBLK), dim3(256), 0, stream,
                       cand, props, reg, bar, scnt, surv, out);
}

// Round 10
// 131.091 us; speedup vs baseline: 1.0690x; 1.0610x over previous
//
#include <hip/hip_runtime.h>
#include <math.h>

#define NPROP 2048
#define NCLS 81
#define NFG 80
#define CAP 512        // per-class candidate cap (mean ~59, huge margin)
#define TOPC 100       // per-class survivors that can matter for global top-100
#define NB 1152        // score histogram buckets
#define BMIN 0x7A99    // bits(0.05f) >> 15

// ws layout:
//   scnt : int[80]       @ 0        (fully written by nms_kernel)
//   surv : ull[80*100]   @ 384      DENSE, stride TOPC (end 64384)
//   cand : ull[80*2048]  @ 65536    CLASS-MAJOR slot map, fully written by k1

#define LDS_FENCE() do { __builtin_amdgcn_wave_barrier(); \
    asm volatile("s_waitcnt lgkmcnt(0)" ::: "memory");     \
    __builtin_amdgcn_wave_barrier(); } while (0)

__device__ __forceinline__ void decode_clip(const float* __restrict__ props,
                                            const float* __restrict__ reg,
                                            int p, int cls, float out[4]) {
    float px1 = props[p * 4 + 0], py1 = props[p * 4 + 1];
    float px2 = props[p * 4 + 2], py2 = props[p * 4 + 3];
    float w = px2 - px1 + 1.0f;
    float h = py2 - py1 + 1.0f;
    float cx = px1 + 0.5f * w;
    float cy = py1 + 0.5f * h;
    const float* r = reg + (size_t)p * (NCLS * 4) + cls * 4;
    float dx = r[0] / 10.0f;
    float dy = r[1] / 10.0f;
    float dw = fminf(r[2] / 5.0f, 4.135166556742356f);
    float dh = fminf(r[3] / 5.0f, 4.135166556742356f);
    float pcx = dx * w + cx;
    float pcy = dy * h + cy;
    float pw = expf(dw) * w;
    float ph = expf(dh) * h;
    float x1 = pcx - 0.5f * pw;
    float y1 = pcy - 0.5f * ph;
    float x2 = pcx + 0.5f * pw - 1.0f;
    float y2 = pcy + 0.5f * ph - 1.0f;
    out[0] = fminf(fmaxf(x1, 0.0f), 1332.0f);
    out[1] = fminf(fmaxf(y1, 0.0f), 799.0f);
    out[2] = fminf(fmaxf(x2, 0.0f), 1332.0f);
    out[3] = fminf(fmaxf(y2, 0.0f), 799.0f);
}

// one wave per proposal row: softmax in registers, write the class-major
// slot map cand[c*2048+p] = valid ? key : 0. No atomics, no memset needed.
__global__ __launch_bounds__(256) void softmax_scatter(const float* __restrict__ logits,
                                                       unsigned long long* __restrict__ cand) {
    int gw = (blockIdx.x * blockDim.x + threadIdx.x) >> 6;
    int lane = threadIdx.x & 63;
    if (gw >= NPROP) return;
    const float* row = logits + (size_t)gw * NCLS;
    float a = row[lane];                       // lane < 64 < 81
    bool hasb = (lane + 64) < NCLS;            // lanes 0..16
    float b = hasb ? row[lane + 64] : -INFINITY;
    float m = fmaxf(a, b);
    #pragma unroll
    for (int s = 32; s; s >>= 1) m = fmaxf(m, __shfl_xor(m, s));
    float ea = expf(a - m);
    float eb = hasb ? expf(b - m) : 0.0f;
    float sum = ea + eb;
    #pragma unroll
    for (int s = 32; s; s >>= 1) sum += __shfl_xor(sum, s);
    float pa = ea / sum;
    float pb = eb / sum;
    unsigned int np = (unsigned int)(~gw);
    if (lane != 0) {                           // c = lane-1 in [0,63)
        cand[(size_t)(lane - 1) * NPROP + gw] = (pa > 0.05f)
            ? (((unsigned long long)__float_as_uint(pa) << 32) | np) : 0ULL;
    }
    if (hasb) {                                // c = lane+63 in [63,80)
        cand[(size_t)(lane + 63) * NPROP + gw] = (pb > 0.05f)
            ? (((unsigned long long)__float_as_uint(pb) << 32) | np) : 0ULL;
    }
}

// ONE WAVE per foreground class. Prefetch the whole 16KB column into
// registers (32 parallel loads), ballot-compact, wave-synchronous sort,
// register-resident greedy NMS, dense survivor writes. No __syncthreads.
__global__ __launch_bounds__(64) void nms_kernel(const unsigned long long* __restrict__ cand,
                                                 const float* __restrict__ props,
                                                 const float* __restrict__ reg,
                                                 int* __restrict__ scnt,
                                                 unsigned long long* __restrict__ surv) {
    const int c = blockIdx.x;
    const int lane = threadIdx.x;
    __shared__ unsigned long long keys[CAP];
    __shared__ float4 bxs[CAP];

    // prefetch column: 32 independent coalesced 512B loads, all in flight
    const unsigned long long* col = cand + (size_t)c * NPROP;
    unsigned long long v[32];
    #pragma unroll
    for (int t = 0; t < 32; ++t) v[t] = col[t * 64 + lane];

    // ballot-compact valid slots in p-ascending order (ties later resolve
    // to smaller p first via ~p in the key low bits)
    int base = 0;
    #pragma unroll
    for (int t = 0; t < 32; ++t) {
        bool keep = v[t] != 0ULL;
        unsigned long long mask = __ballot(keep);
        if (keep) {
            int pos = base + __popcll(mask & ((1ULL << lane) - 1ULL));
            if (pos < CAP) keys[pos] = v[t];
        }
        base += __popcll(mask);
    }
    int M = base > CAP ? CAP : base;
    int nsurv = 0;
    if (M > 0) {
        int S = 64;
        while (S < M) S <<= 1;
        for (int i = lane; i < S; i += 64)
            if (i >= M) keys[i] = 0ULL;
        LDS_FENCE();

        // wave-synchronous bitonic sort descending (pads sink to back)
        for (int k = 2; k <= S; k <<= 1) {
            for (int j = k >> 1; j > 0; j >>= 1) {
                for (int i = lane; i < S; i += 64) {
                    int l = i ^ j;
                    if (l > i) {
                        unsigned long long A = keys[i], B = keys[l];
                        bool dir = ((i & k) == 0);
                        if ((A < B) == dir) { keys[i] = B; keys[l] = A; }
                    }
                }
                LDS_FENCE();
            }
        }

        // decode boxes: own slots to registers, all to LDS for broadcast
        float4 myb[8];
        #pragma unroll
        for (int ns = 0; ns < 8; ++ns) {
            int idx = lane + ns * 64;
            if (idx < M) {
                unsigned long long key = keys[idx];
                int p = (int)(~(unsigned int)key);
                float b4[4];
                decode_clip(props, reg, p, c + 1, b4);
                float4 f = make_float4(b4[0], b4[1], b4[2], b4[3]);
                myb[ns] = f;
                bxs[idx] = f;
            }
        }
        LDS_FENCE();

        // greedy NMS: sequential i, suppression bits in registers
        unsigned int my_sup = 0u;
        for (int i = 0; i < M; ++i) {
            int owner = i & 63, slot = i >> 6;
            unsigned int os = __shfl(my_sup, owner);
            if ((os >> slot) & 1u) continue;   // wave-uniform
            float4 bi = bxs[i];                // broadcast LDS read
            float ai = (bi.z - bi.x + 1.0f) * (bi.w - bi.y + 1.0f);
            #pragma unroll
            for (int ns = 0; ns < 8; ++ns) {
                int j = lane + ns * 64;
                if (j < M && j > i) {
                    float4 bj = myb[ns];
                    float aj = (bj.z - bj.x + 1.0f) * (bj.w - bj.y + 1.0f);
                    float ltx = fmaxf(bi.x, bj.x), lty = fmaxf(bi.y, bj.y);
                    float rbx = fminf(bi.z, bj.z), rby = fminf(bi.w, bj.w);
                    float iw = fmaxf(rbx - ltx + 1.0f, 0.0f);
                    float ih = fmaxf(rby - lty + 1.0f, 0.0f);
                    float inter = iw * ih;
                    float iou = inter / (ai + aj - inter);
                    if (iou > 0.5f) my_sup |= (1u << ns);
                }
            }
        }

        // ballot-compact survivors (descending order), re-key with ~flat;
        // only the first TOPC per class matter -> dense stride TOPC.
        #pragma unroll
        for (int ns = 0; ns < 8; ++ns) {
            if (ns * 64 >= M) break;           // uniform
            int j = lane + ns * 64;
            bool keep = (j < M) && !((my_sup >> ns) & 1u);
            unsigned long long mask = __ballot(keep);
            if (keep) {
                int pos = nsurv + __popcll(mask & ((1ULL << lane) - 1ULL));
                if (pos < TOPC) {
                    unsigned long long key = keys[j];
                    int p = (int)(~(unsigned int)key);
                    unsigned int flat = (unsigned int)(c * NPROP + p);
                    surv[c * TOPC + pos] =
                        (key & 0xFFFFFFFF00000000ULL) | (unsigned int)(~flat);
                }
            }
            nsurv += __popcll(mask);
        }
    }
    if (lane == 0) scnt[c] = nsurv;
}

// single block: radix-select threshold bucket over the dense 64KB survivor
// block, compact ~K>=100 candidates, wave-synchronous sort, emit top-100.
__global__ __launch_bounds__(256) void topk_kernel(const int* __restrict__ scnt,
                                                   const unsigned long long* __restrict__ surv,
                                                   const float* __restrict__ props,
                                                   const float* __restrict__ reg,
                                                   float* __restrict__ out) {
    __shared__ unsigned int hist[NB];
    __shared__ unsigned long long comp[1024];
    __shared__ int s_n[NFG];
    __shared__ int sB;
    __shared__ int compN;
    const int tid = threadIdx.x;

    for (int i = tid; i < NB; i += 256) hist[i] = 0u;
    if (tid < NFG) {
        int k = scnt[tid];
        s_n[tid] = (k > TOPC) ? TOPC : k;
    }
    if (tid == 0) compN = 0;
    __syncthreads();

    // histogram of score high bits (dense reads, fully pipelined)
    for (int idx = tid; idx < NFG * TOPC; idx += 256) {
        int cc = idx / TOPC, i = idx - cc * TOPC;
        if (i < s_n[cc]) {
            unsigned long long key = surv[idx];
            int b = (int)(((unsigned int)(key >> 32)) >> 15) - BMIN;
            b = b < 0 ? 0 : (b >= NB ? NB - 1 : b);
            atomicAdd(&hist[b], 1u);
        }
    }
    __syncthreads();

    // wave 0: suffix-sum from top to find threshold bucket (cum >= 100)
    if (tid < 64) {
        int running = 0, Bstar = 0;
        bool found = false;
        for (int chunk = NB - 64; chunk >= 0; chunk -= 64) {
            int b = chunk + 63 - tid;              // lane 0 = highest bucket
            int s = (int)hist[b];
            #pragma unroll
            for (int d = 1; d < 64; d <<= 1) {
                int o = __shfl_up(s, d);
                if (tid >= d) s += o;
            }
            int cum = running + s;
            unsigned long long m = __ballot(cum >= TOPC);
            if (m != 0ULL) {
                int l = (int)__ffsll((unsigned long long)m) - 1;
                Bstar = chunk + 63 - l;
                found = true;
                break;
            }
            running += __shfl(s, 63);
        }
        if (!found) Bstar = 0;
        if (tid == 0) sB = Bstar;
    }
    __syncthreads();
    int Bstar = sB;

    // compact candidates with bucket >= Bstar (second pass is L2-hot)
    for (int idx = tid; idx < NFG * TOPC; idx += 256) {
        int cc = idx / TOPC, i = idx - cc * TOPC;
        if (i < s_n[cc]) {
            unsigned long long key = surv[idx];
            int b = (int)(((unsigned int)(key >> 32)) >> 15) - BMIN;
            b = b < 0 ? 0 : (b >= NB ? NB - 1 : b);
            if (b >= Bstar) {
                int pos = atomicAdd(&compN, 1);
                if (pos < 1024) comp[pos] = key;
            }
        }
    }
    __syncthreads();
    int K = compN;
    if (K > 1024) K = 1024;
    int P = 128;
    while (P < K) P <<= 1;
    for (int i = K + tid; i < P; i += 256) comp[i] = 0ULL;
    __syncthreads();

    // wave 0: wave-synchronous bitonic sort descending over comp[0..P)
    if (tid < 64) {
        for (int k = 2; k <= P; k <<= 1) {
            for (int j = k >> 1; j > 0; j >>= 1) {
                for (int i = tid; i < P; i += 64) {
                    int l = i ^ j;
                    if (l > i) {
                        unsigned long long A = comp[i], B = comp[l];
                        bool dir = ((i & k) == 0);
                        if ((A < B) == dir) { comp[i] = B; comp[l] = A; }
                    }
                }
                LDS_FENCE();
            }
        }
    }
    __syncthreads();

    if (tid < TOPC) {
        unsigned long long key = comp[tid];
        float score;
        int flat;
        if (key == 0ULL) {             // < 100 total survivors: not expected
            score = -1.0f;
            flat = tid;
        } else {
            score = __uint_as_float((unsigned int)(key >> 32));
            flat = (int)(~(unsigned int)key);
        }
        int cc = flat >> 11;           // NPROP = 2^11
        int p = flat & (NPROP - 1);
        float b4[4];
        decode_clip(props, reg, p, cc + 1, b4);
        out[tid * 4 + 0] = b4[0];
        out[tid * 4 + 1] = b4[1];
        out[tid * 4 + 2] = b4[2];
        out[tid * 4 + 3] = b4[3];
        out[400 + tid] = score;
        out[500 + tid] = (float)(cc + 1);
    }
}

extern "C" void kernel_launch(void* const* d_in, const int* in_sizes, int n_in,
                              void* d_out, int out_size, void* d_ws, size_t ws_size,
                              hipStream_t stream) {
    const float* logits = (const float*)d_in[0];
    const float* reg    = (const float*)d_in[1];
    const float* props  = (const float*)d_in[2];
    float* out = (float*)d_out;

    int* scnt = (int*)d_ws;
    unsigned long long* surv = (unsigned long long*)((char*)d_ws + 384);
    unsigned long long* cand = (unsigned long long*)((char*)d_ws + 65536);

    hipLaunchKernelGGL(softmax_scatter, dim3((NPROP * 64) / 256), dim3(256), 0, stream,
                       logits, cand);
    hipLaunchKernelGGL(nms_kernel, dim3(NFG), dim3(64), 0, stream,
                       cand, props, reg, scnt, surv);
    hipLaunchKernelGGL(topk_kernel, dim3(1), dim3(256), 0, stream,
                       scnt, surv, props, reg, out);
}